// Round 2
// 78.389 us; speedup vs baseline: 1.0097x; 1.0097x over previous
//
#include <hip/hip_runtime.h>

#define NIN 5
#define POL 55
#define NW 69
#define ROWS_PER_THREAD 4
#define BLOCK 256
#define TILE (BLOCK * ROWS_PER_THREAD)

// Fused kernel, v2 (re-run; round-1 bench was an infra failure).
//
// v1 was LDS-issue-bound: the row loop re-read all 65 coefficients from LDS
// per row (260 ds_read_b32/thread; ~1.0M wave-level ds_reads ~= 38 us at the
// measured 5.8 cyc/ds_read throughput). Coefficients are wave-uniform, so v2
// hoists them ONCE through readfirstlane into SGPRs; the polynomial/trig loop
// is then pure VALU (v_fma with one scalar operand) + VMEM.
//
// LDS layout (parse phase, unchanged from v1):
//   w[0..4]   A_j        (degree-1 coefs)
//   w[5..19]  B_{j<=k}   (degree-2, triangular order)
//   w[20..54] C_{j<=k<=l}(degree-3, triangular order)
//   w[55..59] cos coefs  w[60..64] sin coefs
//   w[65]=omegas[0] w[66]=omegas[1] w[67]=filt[0] w[68]=filt[1]

__device__ __forceinline__ float uniform_load(const float* p) {
    int bits = __builtin_amdgcn_readfirstlane(__float_as_int(*p));
    return __int_as_float(bits);
}

__device__ __forceinline__ float eval_row(const float cw[NW], float w0, float w1,
                                          float4 xv, float tv) {
    float v[NIN] = {xv.x, xv.y, xv.z, xv.w, tv};

    // Trig first: long-latency trans-pipe ops overlap the FMA chain below.
    float s = 0.f;
    #pragma unroll
    for (int j = 0; j < NIN; ++j) {
        s = fmaf(cw[55 + j], __cosf(w0 * v[j]), s);
        s = fmaf(cw[60 + j], __sinf(w1 * v[j]), s);
    }

    // s += sum_j v_j * ( A_j + sum_{k>=j} v_k * ( B_jk + sum_{l>=k} C_jkl v_l ) )
    int i2 = 5, i3 = 20;
    #pragma unroll
    for (int j = 0; j < NIN; ++j) {
        float qj = 0.f;
        #pragma unroll
        for (int kk = j; kk < NIN; ++kk) {
            float rr = cw[i2++];
            #pragma unroll
            for (int l = kk; l < NIN; ++l) rr = fmaf(cw[i3++], v[l], rr);
            qj = fmaf(rr, v[kk], qj);
        }
        s = fmaf(v[j], cw[j] + qj, s);
    }
    return s;
}

__global__ __launch_bounds__(BLOCK) void fused_kernel(
    const float4* __restrict__ x,     // N rows of 4 states
    const float* __restrict__ t,      // N time values
    const float* __restrict__ layer,
    const float* __restrict__ omegas,
    const float* __restrict__ ext_filter,
    const int* __restrict__ E,
    float2* __restrict__ out,         // N float2 rows
    int n) {
    __shared__ float w[NW];
    int k = threadIdx.x;
    if (k < POL) {
        int e[NIN];
        int d = 0;
        #pragma unroll
        for (int j = 0; j < NIN; ++j) { e[j] = E[k * NIN + j]; d += e[j]; }
        // expand exponents into sorted variable multiset (size d <= 3)
        int vars[3] = {0, 0, 0};
        int c = 0;
        for (int j = 0; j < NIN; ++j)
            for (int r = 0; r < e[j]; ++r) vars[c++] = j;
        int slot;
        if (d == 1) {
            slot = vars[0];
        } else if (d == 2) {
            int j = vars[0], kk = vars[1];
            slot = 5 + j * NIN - j * (j - 1) / 2 + (kk - j);
        } else {
            const int base3[5] = {0, 15, 25, 31, 34};
            int j = vars[0], kk = vars[1], l = vars[2];
            int m = NIN - j;
            int a = kk - j;
            slot = 20 + base3[j] + a * m - a * (a - 1) / 2 + (l - kk);
        }
        w[slot] = layer[k];
    } else if (k < POL + 10) {
        w[k] = layer[k];              // trig coefficients pass through
    } else if (k == POL + 10) {
        w[65] = omegas[0];
        w[66] = omegas[1];
        w[67] = ext_filter[0];
        w[68] = ext_filter[1];
    }
    __syncthreads();

    // Hoist ALL coefficients out of LDS exactly once. Values are wave-uniform,
    // so readfirstlane legally pins them in SGPRs: the hot loop then costs
    // zero LDS issue slots and near-zero VGPR for coefficients.
    float cw[NW];
    #pragma unroll
    for (int i = 0; i < NW; ++i)
        cw[i] = uniform_load(&w[i]);

    const float w0 = cw[65], w1 = cw[66];
    const float f0 = cw[67], f1 = cw[68];

    const int base = blockIdx.x * TILE + threadIdx.x;
    const bool full = (blockIdx.x * TILE + TILE) <= n;   // block-uniform

    if (full) {
        // Fast path: no per-row bounds branch -> all 8 loads issue up front.
        float4 xv[ROWS_PER_THREAD];
        float  tv[ROWS_PER_THREAD];
        #pragma unroll
        for (int r = 0; r < ROWS_PER_THREAD; ++r) {
            xv[r] = x[base + r * BLOCK];
            tv[r] = t[base + r * BLOCK];
        }
        #pragma unroll
        for (int r = 0; r < ROWS_PER_THREAD; ++r) {
            float s = eval_row(cw, w0, w1, xv[r], tv[r]);
            out[base + r * BLOCK] = make_float2(s * f0, s * f1);
        }
    } else {
        #pragma unroll
        for (int r = 0; r < ROWS_PER_THREAD; ++r) {
            int row = base + r * BLOCK;
            if (row < n) {
                float s = eval_row(cw, w0, w1, x[row], t[row]);
                out[row] = make_float2(s * f0, s * f1);
            }
        }
    }
}

extern "C" void kernel_launch(void* const* d_in, const int* in_sizes, int n_in,
                              void* d_out, int out_size, void* d_ws, size_t ws_size,
                              hipStream_t stream) {
    const float* x          = (const float*)d_in[0];
    const float* t          = (const float*)d_in[1];
    const float* layer      = (const float*)d_in[2];
    const float* omegas     = (const float*)d_in[3];
    const float* ext_filter = (const float*)d_in[4];
    const int*   E          = (const int*)d_in[5];

    int n = in_sizes[1];      // N_DATA (t has one element per row)

    fused_kernel<<<(n + TILE - 1) / TILE, BLOCK, 0, stream>>>(
        (const float4*)x, t, layer, omegas, ext_filter, E,
        (float2*)d_out, n);
}